// Round 3
// baseline (238.654 us; speedup 1.0000x reference)
//
#include <hip/hip_runtime.h>

// Shapes: N=8, C=512, T=8, H=32, W=32, HW=1024, THW=8192, CI=256, CA=128
// All float inputs/outputs are FLOAT32 (npz-size evidence: in 126.5MB / out
// 124.4MB ~= f32 raw sizes compressed; bf16 would be half and is impossible).
//
// Factorization (phi(audio) constant over h,w):
//   at[n,t,c]   = relu(audio[n,t,:]·alignW[c,:] + alignB[c])          (output 2)
//   phi[n,i,t]  = Wph[i,:]·at[n,t,:] + bph[i]
//   M[n,c,t]    = sum_i Wth[i,c]·phi[n,i,t];  const[n,t] = sum_i bth[i]·phi[n,i,t]
//   Xsum[n,c,t] = sum_hw x[n,c,t,hw]
//   G[n,t,o]    = Wg[o,:]·Xsum[n,:,t] + 1024·bg[o];  GW[n,t,c] = Wz[c,:]·G[n,t,:]
//   f[n,s,t]    = x[n,:,s]·M[n,:,t] + const[n,t]
//   W_y[n,s,c]  = (1/8192)·sum_t f[n,s,t]·GW[n,t,c] + bz[c]
//   BN stats from F[n,t]=sum_s f and S2[n,t1,t2]=sum_s f·f^T  (W_y never stored)
//   z = LN_c(0.5·BN(W_y) + 0.5·x)                                    (output 1)

// ---------------- audio -> at -> phi -> M, const ----------------
__global__ __launch_bounds__(256) void k_small1(
    const float* __restrict__ audio, const float* __restrict__ alignW, const float* __restrict__ alignB,
    const float* __restrict__ Wph, const float* __restrict__ bph,
    const float* __restrict__ Wth, const float* __restrict__ bth,
    float* __restrict__ outA, float* __restrict__ constT, float* __restrict__ M)
{
    int b = blockIdx.x; int n = b >> 3; int t = b & 7; int tid = threadIdx.x;
    __shared__ float al[128];
    __shared__ float atl[512];
    __shared__ float phil[256];
    __shared__ float red[256];
    if (tid < 128) al[tid] = audio[(n * 8 + t) * 128 + tid];
    __syncthreads();
    for (int c = tid; c < 512; c += 256) {      // at[n,t,c] (also output 2)
        float acc = alignB[c];
        for (int k = 0; k < 128; ++k) acc += al[k] * alignW[c * 128 + k];
        acc = fmaxf(acc, 0.f);
        atl[c] = acc;
        outA[(n * 8 + t) * 512 + c] = acc;
    }
    __syncthreads();
    {                                           // phi[n,i,t], i = tid
        int i = tid;
        float acc = bph[i];
        for (int c = 0; c < 512; ++c) acc += Wph[i * 512 + c] * atl[c];
        phil[i] = acc;
        red[i] = acc * bth[i];
    }
    __syncthreads();
    for (int sr = 128; sr > 0; sr >>= 1) {      // const[n,t] = sum_i phi*bth
        if (tid < sr) red[tid] += red[tid + sr];
        __syncthreads();
    }
    if (tid == 0) constT[n * 8 + t] = red[0];
    for (int c = tid; c < 512; c += 256) {      // M[n,c,t]
        float acc = 0.f;
        for (int i = 0; i < 256; ++i) acc += Wth[i * 512 + c] * phil[i];
        M[n * 4096 + c * 8 + t] = acc;
    }
}

// ---------------- Xsum: one 64-lane wave per (n,c,t) row of 1024 ----------------
__global__ __launch_bounds__(64) void k_xsum(const float* __restrict__ x, float* __restrict__ xs)
{
    int b = blockIdx.x; int tid = threadIdx.x;
    const float4* p = reinterpret_cast<const float4*>(x + (size_t)b * 1024);
    float s = 0.f;
    for (int k = 0; k < 4; ++k) {
        float4 v = p[tid + 64 * k];
        s += v.x + v.y + v.z + v.w;
    }
    for (int off = 32; off > 0; off >>= 1) s += __shfl_down(s, off);
    if (tid == 0) xs[b] = s;
}

// ---------------- G then GW ----------------
__global__ __launch_bounds__(256) void k_small2(
    const float* __restrict__ xs, const float* __restrict__ Wg, const float* __restrict__ bg,
    const float* __restrict__ Wz, float* __restrict__ GW)
{
    int b = blockIdx.x; int n = b >> 3; int t = b & 7; int tid = threadIdx.x;
    __shared__ float xsl[512];
    __shared__ float gl[256];
    for (int c = tid; c < 512; c += 256) xsl[c] = xs[(n * 512 + c) * 8 + t];
    __syncthreads();
    {                                           // G[n,t,o], o = tid
        int o = tid;
        float acc = 1024.f * bg[o];
        for (int c = 0; c < 512; ++c) acc += Wg[o * 512 + c] * xsl[c];
        gl[o] = acc;
    }
    __syncthreads();
    for (int c = tid; c < 512; c += 256) {      // GW[n,t,c]
        float acc = 0.f;
        for (int o = 0; o < 256; ++o) acc += Wz[c * 256 + o] * gl[o];
        GW[(n * 8 + t) * 512 + c] = acc;
    }
}

// ---------------- f[n,s,0..7] ----------------
__global__ __launch_bounds__(256) void k_fsmall(
    const float* __restrict__ x, const float* __restrict__ M,
    const float* __restrict__ constT, float* __restrict__ fs)
{
    int b = blockIdx.x; int n = b >> 5; int s0 = (b & 31) << 8;
    int s = s0 + threadIdx.x;
    const float* Mb = M + n * 4096;
    const float* xb = x + (size_t)n * 4194304 + s;
    float p[8] = {0, 0, 0, 0, 0, 0, 0, 0};
    for (int c = 0; c < 512; ++c) {
        float xv = xb[(size_t)c * 8192];
        float4 m0 = *reinterpret_cast<const float4*>(Mb + c * 8);
        float4 m1 = *reinterpret_cast<const float4*>(Mb + c * 8 + 4);
        p[0] += xv * m0.x; p[1] += xv * m0.y; p[2] += xv * m0.z; p[3] += xv * m0.w;
        p[4] += xv * m1.x; p[5] += xv * m1.y; p[6] += xv * m1.z; p[7] += xv * m1.w;
    }
    const float* ct = constT + n * 8;
    float4 o0 = make_float4(p[0] + ct[0], p[1] + ct[1], p[2] + ct[2], p[3] + ct[3]);
    float4 o1 = make_float4(p[4] + ct[4], p[5] + ct[5], p[6] + ct[6], p[7] + ct[7]);
    float4* op = reinterpret_cast<float4*>(fs + ((size_t)n * 8192 + s) * 8);
    op[0] = o0; op[1] = o1;
}

// ---------------- F[n,t], S2[n,t1,t2] ----------------
__global__ __launch_bounds__(256) void k_f2(
    const float* __restrict__ fs, float* __restrict__ F, float* __restrict__ S2)
{
    int n = blockIdx.x; int tid = threadIdx.x;
    int lane = tid & 63, wv = tid >> 6;
    float fsum[8];
    float s2[36];
    for (int k = 0; k < 8; ++k) fsum[k] = 0.f;
    for (int k = 0; k < 36; ++k) s2[k] = 0.f;
    for (int s = tid; s < 8192; s += 256) {
        const float4* p4 = reinterpret_cast<const float4*>(fs + ((size_t)n * 8192 + s) * 8);
        float4 a = p4[0], b4 = p4[1];
        float p[8] = {a.x, a.y, a.z, a.w, b4.x, b4.y, b4.z, b4.w};
        int idx = 0;
        for (int t1 = 0; t1 < 8; ++t1) {
            fsum[t1] += p[t1];
            for (int t2 = t1; t2 < 8; ++t2) { s2[idx] += p[t1] * p[t2]; ++idx; }
        }
    }
    for (int k = 0; k < 8; ++k)
        for (int off = 32; off > 0; off >>= 1) fsum[k] += __shfl_down(fsum[k], off);
    for (int k = 0; k < 36; ++k)
        for (int off = 32; off > 0; off >>= 1) s2[k] += __shfl_down(s2[k], off);
    __shared__ float part[4][44];
    if (lane == 0) {
        for (int k = 0; k < 8; ++k) part[wv][k] = fsum[k];
        for (int k = 0; k < 36; ++k) part[wv][8 + k] = s2[k];
    }
    __syncthreads();
    if (tid < 44) {
        float v = part[0][tid] + part[1][tid] + part[2][tid] + part[3][tid];
        if (tid < 8) F[n * 8 + tid] = v;
        else {
            int kk = tid - 8; int t1 = 0;
            while (kk >= 8 - t1) { kk -= 8 - t1; ++t1; }
            int t2 = t1 + kk;
            S2[n * 64 + t1 * 8 + t2] = v;
            S2[n * 64 + t2 * 8 + t1] = v;
        }
    }
}

// ---------------- BN stats (closed form) -> folded tables ----------------
__global__ __launch_bounds__(512) void k_bn(
    const float* __restrict__ F, const float* __restrict__ S2, const float* __restrict__ GW,
    const float* __restrict__ bz, const float* __restrict__ bng, const float* __restrict__ bnb,
    const float* __restrict__ lng, const float* __restrict__ lnb,
    float* __restrict__ pack0, float* __restrict__ gw2)
{
    int n0 = blockIdx.x; int c = threadIdx.x;
    __shared__ float Fl[64];
    __shared__ float S2l[512];
    if (c < 64) Fl[c] = F[c];
    S2l[c] = S2[c];
    __syncthreads();
    const float r = 1.f / 8192.f;
    float meanu = 0.f, e2 = 0.f;
    for (int n = 0; n < 8; ++n) {
        float g[8];
        for (int t = 0; t < 8; ++t) g[t] = GW[(n * 8 + t) * 512 + c];
        for (int t = 0; t < 8; ++t) meanu += Fl[n * 8 + t] * g[t];
        for (int t1 = 0; t1 < 8; ++t1)
            for (int t2 = 0; t2 < 8; ++t2) e2 += S2l[n * 64 + t1 * 8 + t2] * g[t1] * g[t2];
    }
    const float invCnt = 1.f / 65536.f;
    meanu *= r * invCnt;
    e2 *= r * r * invCnt;
    float var = fmaxf(e2 - meanu * meanu, 0.f);
    float bzv = bz[c];
    float mean = meanu + bzv;
    float sc = bng[c] * rsqrtf(var + 1e-5f);
    float sh = bnb[c] - mean * sc;
    if (n0 == 0) {
        float4 pk;
        pk.x = 0.5f * (bzv * sc + sh);   // constant part of 0.5*BN(W_y)
        pk.y = lng[c];
        pk.z = lnb[c];
        pk.w = 0.f;
        *reinterpret_cast<float4*>(pack0 + c * 4) = pk;
    }
    float scale = 0.5f * r * sc;
    for (int t = 0; t < 8; ++t)
        gw2[((size_t)n0 * 512 + c) * 8 + t] = GW[(n0 * 8 + t) * 512 + c] * scale;
}

// ---------------- fused W_y reconstruct + blend + LayerNorm ----------------
__global__ __launch_bounds__(256) void k_final(
    const float* __restrict__ x, const float* __restrict__ fs,
    const float* __restrict__ pack0, const float* __restrict__ gw2,
    float* __restrict__ outZ)
{
    int b = blockIdx.x; int n = b >> 5; int s0 = (b & 31) << 8;
    int tid = threadIdx.x; int lane = tid & 63; int wv = tid >> 6;
    __shared__ float redS[2][4][256];
    float4 fdA[4], fdB[4];
    for (int k = 0; k < 4; ++k) {
        const float4* fp = reinterpret_cast<const float4*>(fs + ((size_t)n * 8192 + s0 + k * 64 + lane) * 8);
        fdA[k] = fp[0]; fdB[k] = fp[1];
    }
    const size_t xbase = (size_t)n * 4194304 + s0 + lane;
    float s1[4] = {0, 0, 0, 0}, sq[4] = {0, 0, 0, 0};
    for (int j = 0; j < 128; ++j) {
        int c = wv * 128 + j;                    // wave-uniform channel
        const float* gp = gw2 + ((size_t)n * 512 + c) * 8;
        float4 g0 = *reinterpret_cast<const float4*>(gp);
        float4 g1 = *reinterpret_cast<const float4*>(gp + 4);
        float sh2 = pack0[c * 4];
        for (int k = 0; k < 4; ++k) {
            float xv = x[xbase + (size_t)c * 8192 + k * 64];
            float zp = sh2 + 0.5f * xv
                + fdA[k].x * g0.x + fdA[k].y * g0.y + fdA[k].z * g0.z + fdA[k].w * g0.w
                + fdB[k].x * g1.x + fdB[k].y * g1.y + fdB[k].z * g1.z + fdB[k].w * g1.w;
            s1[k] += zp; sq[k] += zp * zp;
        }
    }
    for (int k = 0; k < 4; ++k) { redS[0][wv][k * 64 + lane] = s1[k]; redS[1][wv][k * 64 + lane] = sq[k]; }
    __syncthreads();
    float mean[4], rstd[4];
    for (int k = 0; k < 4; ++k) {
        int ix = k * 64 + lane;
        float a = redS[0][0][ix] + redS[0][1][ix] + redS[0][2][ix] + redS[0][3][ix];
        float q = redS[1][0][ix] + redS[1][1][ix] + redS[1][2][ix] + redS[1][3][ix];
        mean[k] = a * (1.f / 512.f);
        float var = fmaxf(q * (1.f / 512.f) - mean[k] * mean[k], 0.f);
        rstd[k] = rsqrtf(var + 1e-5f);
    }
    for (int j = 0; j < 128; ++j) {
        int c = wv * 128 + j;
        const float* gp = gw2 + ((size_t)n * 512 + c) * 8;
        float4 g0 = *reinterpret_cast<const float4*>(gp);
        float4 g1 = *reinterpret_cast<const float4*>(gp + 4);
        float4 pk = *reinterpret_cast<const float4*>(pack0 + c * 4);
        for (int k = 0; k < 4; ++k) {
            float xv = x[xbase + (size_t)c * 8192 + k * 64];
            float zp = pk.x + 0.5f * xv
                + fdA[k].x * g0.x + fdA[k].y * g0.y + fdA[k].z * g0.z + fdA[k].w * g0.w
                + fdB[k].x * g1.x + fdB[k].y * g1.y + fdB[k].z * g1.z + fdB[k].w * g1.w;
            float o = (zp - mean[k]) * rstd[k] * pk.y + pk.z;
            outZ[xbase + (size_t)c * 8192 + k * 64] = o;
        }
    }
}

extern "C" void kernel_launch(void* const* d_in, const int* in_sizes, int n_in,
                              void* d_out, int out_size, void* d_ws, size_t ws_size,
                              hipStream_t stream)
{
    const float* x      = (const float*)d_in[0];
    const float* audio  = (const float*)d_in[1];
    const float* alignW = (const float*)d_in[2];
    const float* alignB = (const float*)d_in[3];
    const float* Wg     = (const float*)d_in[4];
    const float* bg     = (const float*)d_in[5];
    const float* Wth    = (const float*)d_in[6];
    const float* bth    = (const float*)d_in[7];
    const float* Wph    = (const float*)d_in[8];
    const float* bph    = (const float*)d_in[9];
    const float* Wz     = (const float*)d_in[10];
    const float* bz     = (const float*)d_in[11];
    const float* bng    = (const float*)d_in[12];
    const float* bnb    = (const float*)d_in[13];
    const float* lng    = (const float*)d_in[14];
    const float* lnb    = (const float*)d_in[15];
    float* outZ = (float*)d_out;
    float* outA = outZ + 33554432;  // z (N,C,T,H,W) then audio_temp (N,T,C)

    // 256B-aligned workspace; zero it (read-before-write insurance).
    uintptr_t pa = ((uintptr_t)d_ws + 255) & ~(uintptr_t)255;
    float* w = (float*)pa;
    hipMemsetAsync((void*)pa, 0, 658048 * sizeof(float), stream);

    float* constT = w;              // 64
    float* M      = w + 64;         // 32768  [n][c][t]
    float* XS     = w + 32832;      // 32768  [(n,c,t) linear]
    float* GW     = w + 65600;      // 32768  [n][t][c]
    float* Fs     = w + 98368;      // 64
    float* S2     = w + 98432;      // 512
    float* pack0  = w + 98944;      // 2048   float4 per c: {sh2, ln_g, ln_b, 0}
    float* gw2    = w + 100992;     // 32768  [n][c][t] folded with 0.5*r*bn_scale
    float* fsm    = w + 133760;     // 524288 [n][s][t]

    k_small1<<<64, 256, 0, stream>>>(audio, alignW, alignB, Wph, bph, Wth, bth, outA, constT, M);
    k_xsum<<<32768, 64, 0, stream>>>(x, XS);
    k_small2<<<64, 256, 0, stream>>>(XS, Wg, bg, Wz, GW);
    k_fsmall<<<256, 256, 0, stream>>>(x, M, constT, fsm);
    k_f2<<<8, 256, 0, stream>>>(fsm, Fs, S2);
    k_bn<<<8, 512, 0, stream>>>(Fs, S2, GW, bz, bng, bnb, lng, lnb, pack0, gw2);
    k_final<<<256, 256, 0, stream>>>(x, fsm, pack0, gw2, outZ);
}